// Round 8
// baseline (268.054 us; speedup 1.0000x reference)
//
#include <hip/hip_runtime.h>
#include <hip/hip_bf16.h>

typedef unsigned short u16;
typedef __attribute__((ext_vector_type(4))) float  f32x4;
typedef __attribute__((ext_vector_type(8))) short  s16x8;
typedef __attribute__((ext_vector_type(4))) short  s16x4;
typedef __attribute__((ext_vector_type(4))) int    i32x4;
typedef __attribute__((ext_vector_type(2))) unsigned int u32x2;

#define MFMA32(a,b,c) __builtin_amdgcn_mfma_f32_16x16x32_bf16((a),(b),(c),0,0,0)

__device__ __forceinline__ short f2bf(float f) {
  unsigned u = __float_as_uint(f);
  u = (u + 0x7fffu + ((u >> 16) & 1u)) >> 16;
  return (short)u;
}
__device__ __forceinline__ unsigned packbf(float lo, float hi) {
  return (unsigned)(u16)f2bf(lo) | ((unsigned)(u16)f2bf(hi) << 16);
}
// packed RNE f32x2 -> bf16x2 (v_cvt_pk_bf16_f32)
__device__ __forceinline__ unsigned cvtpk(float a, float b) {
  float2 f; f.x = a; f.y = b;
  __hip_bfloat162 h = __float22bfloat162_rn(f);
  unsigned u; __builtin_memcpy(&u, &h, 4); return u;
}

// Geometry: B=16,T=4096,C=256 -> 256 windows of W=256, H=4, DH=64, RADIUS=32 (33 keys/row)

// ---------------- K0: weight cast + transpose ----------------
__global__ __launch_bounds__(256) void k_prep(const float* __restrict__ wqkv,
                                              const float* __restrict__ wproj,
                                              u16* __restrict__ wqkvT,
                                              u16* __restrict__ wprojT) {
  int idx = blockIdx.x * 256 + threadIdx.x;
  if (idx < 768 * 256) {
    int n = idx >> 8, kk = idx & 255;
    wqkvT[idx] = (u16)f2bf(wqkv[kk * 768 + n]);
  } else {
    int j = idx - 768 * 256;            // 0 .. 65535
    int n = j >> 8, kk = j & 255;
    wprojT[j] = (u16)f2bf(wproj[kk * 256 + n]);
  }
}

// ---------------- K1: qkv = x @ Wqkv  (rows = nm*128, N=768, K=256), bf16 out ----------------
// v3: A-tile (128 x 256) staged to LDS ONCE (one barrier/block), then 6 barrier-free
// N-iterations; B read directly from L2-resident wqkvT. 512 thr, 2 blocks/CU (50% occ).
__global__ __launch_bounds__(512, 4) void k_qkv(const float* __restrict__ x,
                                                const u16* __restrict__ wqkvT,
                                                u16* __restrict__ qkvws,
                                                int whichStride, int nmTiles) {
  __shared__ u16 Ash[128 * 256];        // 64 KB, XOR-swizzled rows
  const int tid = threadIdx.x;
  const int lane = tid & 63, wid = tid >> 6;
  const int wm = wid & 1, wn = wid >> 1;   // wave tile: 64M x 32N
  const int c15 = lane & 15, g = lane >> 4;

  // XCD-aware: contiguous M-range per XCD (bijective iff nmTiles % 8 == 0)
  int bidx = blockIdx.x, m;
  if ((nmTiles & 7) == 0) { int xcd = bidx & 7, t = bidx >> 3; m = xcd * (nmTiles >> 3) + t; }
  else m = bidx;
  const size_t Mbase = (size_t)m * 128;

  // ---- stage x tile -> LDS bf16 (coalesced 64B groups; 16 loads + 16 b64 writes/thread) ----
  {
    const int row = tid >> 2, q = tid & 3;
    const float* xp = x + (Mbase + row) * 256 + q * 4;
    const unsigned swz = ((unsigned)(row & 7)) << 4;
#pragma unroll
    for (int p = 0; p < 16; ++p) {
      f32x4 v = *(const f32x4*)(xp + p * 16);
      u32x2 pk = { cvtpk(v[0], v[1]), cvtpk(v[2], v[3]) };
      unsigned b = ((unsigned)(row * 512 + p * 32 + q * 8)) ^ swz;
      *(u32x2*)((char*)Ash + b) = pk;
    }
  }
  __syncthreads();   // the ONLY barrier in this kernel

  // ---- 6 N-blocks of 128, barrier-free ----
  for (int nIdx = 0; nIdx < 6; ++nIdx) {
    const int Nbase = nIdx * 128;
    f32x4 acc[4][2] = {};               // [mt][nt]
#pragma unroll
    for (int kc = 0; kc < 8; ++kc) {    // K = 8 x 32
      s16x8 af[4], bf[2];
#pragma unroll
      for (int mt = 0; mt < 4; ++mt) {
        int row = wm * 64 + mt * 16 + c15;
        unsigned b = ((unsigned)(row * 512 + kc * 64 + g * 16)) ^ (((unsigned)(row & 7)) << 4);
        af[mt] = *(const s16x8*)((const char*)Ash + b);
      }
#pragma unroll
      for (int nt = 0; nt < 2; ++nt) {
        int n = Nbase + wn * 32 + nt * 16 + c15;
        bf[nt] = *(const s16x8*)(wqkvT + n * 256 + kc * 32 + g * 8);
      }
#pragma unroll
      for (int mt = 0; mt < 4; ++mt)
#pragma unroll
        for (int nt = 0; nt < 2; ++nt)
          acc[mt][nt] = MFMA32(af[mt], bf[nt], acc[mt][nt]);
    }
    // scattered bf16 stores (proven non-limiting r6/r7); n -> (which,h,d)
#pragma unroll
    for (int nt = 0; nt < 2; ++nt) {
      int n = Nbase + wn * 32 + nt * 16 + c15;
      int which = n >> 8, h = (n >> 6) & 3, dd = n & 63;
      size_t o0 = (size_t)which * whichStride + (size_t)h * 16384 + dd;
#pragma unroll
      for (int mt = 0; mt < 4; ++mt)
#pragma unroll
        for (int r = 0; r < 4; ++r) {
          size_t mg = Mbase + wm * 64 + mt * 16 + g * 4 + r;
          qkvws[o0 + (mg >> 8) * 65536 + (mg & 255) * 64] = (u16)f2bf(acc[mt][nt][r]);
        }
    }
  }
}

// ---------------- K2: per-window banded attention + output projection ----------------
__global__ __launch_bounds__(512) void k_attn_proj(const u16* __restrict__ qws,
                                                   const u16* __restrict__ kws,
                                                   const u16* __restrict__ vws,
                                                   const u16* __restrict__ wprojT,
                                                   const float* __restrict__ bias,
                                                   float* __restrict__ out) {
  __shared__ u16 Osh[256 * 256];  // attn output [row][C] bf16, XOR-swizzled, 128 KiB
  const int tid = threadIdx.x;
  const int lane = tid & 63, wid = tid >> 6;
  const int head = wid >> 1, qhalf = wid & 1;
  const int c15 = lane & 15, g = lane >> 4;
  const int win = blockIdx.x;

  const size_t hb = (size_t)(win * 4 + head) * 16384;  // 256*64 per (win,head)
  const u16* Qp = qws + hb;
  const u16* Kp = kws + hb;
  const u16* Vp = vws + hb;
  const int start = qhalf * 8;          // this wave's Q-tiles: [start, start+8); start % 4 == 0

  // 4-slot register rings (slot = jt & 3): K fragments (A-layout) and V fragments (B-layout)
  s16x8 klo[4] = {}, khi[4] = {};
  s16x8 vfr[4][4] = {};

#define LOADKV(jt, slot) do {                                                \
    const u16* _p = Kp + (jt) * 1024 + c15 * 64 + g * 8;                     \
    klo[slot] = *(const s16x8*)_p;                                           \
    khi[slot] = *(const s16x8*)(_p + 32);                                    \
    const int _rb = (jt) * 16 + ((g & 1) << 3);                              \
    _Pragma("unroll")                                                        \
    for (int _dt = 0; _dt < 4; ++_dt) {                                      \
      s16x8 _t;                                                              \
      _Pragma("unroll")                                                      \
      for (int _i = 0; _i < 8; ++_i)                                         \
        _t[_i] = (short)Vp[(_rb + _i) * 64 + _dt * 16 + c15];                \
      vfr[slot][_dt] = _t;                                                   \
    }                                                                        \
  } while (0)

  if (start >= 2) LOADKV(start - 2, 2);
  if (start >= 1) LOADKV(start - 1, 3);
  LOADKV(start, 0);

#pragma unroll
  for (int ii = 0; ii < 8; ++ii) {
    const int i16 = start + ii;
    const int sP = (ii + 1) & 3;
    const int s0 = ii & 3;
    const int s1 = (ii + 3) & 3;
    const int s2 = (ii + 2) & 3;
    if (ii < 7) LOADKV(i16 + 1, sP);   // prefetch next K/V tile

    const u16* qp = Qp + i16 * 1024 + c15 * 64 + g * 8;
    const s16x8 qf0 = *(const s16x8*)qp;
    const s16x8 qf1 = *(const s16x8*)(qp + 32);

    // S^T[j][q] = sum_d K[j][d] Q[q][d]; lane holds j = jt*16 + g*4 + r, q = c15
    f32x4 sT0 = {}, sT1 = {}, sT2 = {};
    sT0 = MFMA32(klo[s0], qf0, sT0);
    sT0 = MFMA32(khi[s0], qf1, sT0);
    if (i16 >= 1) { sT1 = MFMA32(klo[s1], qf0, sT1); sT1 = MFMA32(khi[s1], qf1, sT1); }
    if (i16 >= 2) { sT2 = MFMA32(klo[s2], qf0, sT2); sT2 = MFMA32(khi[s2], qf1, sT2); }

    const int qrow = i16 * 16 + c15;
    float e0[4], e1[4], e2[4];
    float vmax = -3.0e38f;
#pragma unroll
    for (int r = 0; r < 4; ++r) {
      int dd = qrow - (i16 * 16 + g * 4 + r);
      e0[r] = (dd >= 0 && dd <= 32) ? sT0[r] * 0.125f : -1.0e30f;
      vmax = fmaxf(vmax, e0[r]);
    }
    if (i16 >= 1) {
#pragma unroll
      for (int r = 0; r < 4; ++r) {           // dd in 1..31, always in band
        e1[r] = sT1[r] * 0.125f;
        vmax = fmaxf(vmax, e1[r]);
      }
    }
    if (i16 >= 2) {
#pragma unroll
      for (int r = 0; r < 4; ++r) {
        int dd = qrow - ((i16 - 2) * 16 + g * 4 + r);   // 17..47
        e2[r] = (dd <= 32) ? sT2[r] * 0.125f : -1.0e30f;
        vmax = fmaxf(vmax, e2[r]);
      }
    }
    vmax = fmaxf(vmax, __shfl_xor(vmax, 16));
    vmax = fmaxf(vmax, __shfl_xor(vmax, 32));
    float ssum = 0.0f;
#pragma unroll
    for (int r = 0; r < 4; ++r) { e0[r] = __expf(e0[r] - vmax); ssum += e0[r]; }
    if (i16 >= 1) {
#pragma unroll
      for (int r = 0; r < 4; ++r) { e1[r] = __expf(e1[r] - vmax); ssum += e1[r]; }
    }
    if (i16 >= 2) {
#pragma unroll
      for (int r = 0; r < 4; ++r) { e2[r] = __expf(e2[r] - vmax); ssum += e2[r]; }
    }
    ssum += __shfl_xor(ssum, 16);
    ssum += __shfl_xor(ssum, 32);
    const float inv = 1.0f / ssum;

    unsigned c0a = packbf(e0[0] * inv, e0[1] * inv), c0b = packbf(e0[2] * inv, e0[3] * inv);
    unsigned c1a = 0, c1b = 0, c2a = 0, c2b = 0;
    if (i16 >= 1) { c1a = packbf(e1[0] * inv, e1[1] * inv); c1b = packbf(e1[2] * inv, e1[3] * inv); }
    if (i16 >= 2) { c2a = packbf(e2[0] * inv, e2[1] * inv); c2b = packbf(e2[2] * inv, e2[3] * inv); }

    const int src0 = ((g & 1) << 5) + c15;
    const int src1 = src0 + 16;
    const bool alo = (g < 2);
#define MKFRAG(pa, ua, ub) do {                                             \
      int _t0 = __shfl((int)(ua), src0), _t1 = __shfl((int)(ub), src0);     \
      int _t2 = __shfl((int)(ua), src1), _t3 = __shfl((int)(ub), src1);     \
      i32x4 _ti = { alo ? _t0 : 0, alo ? _t1 : 0, alo ? _t2 : 0, alo ? _t3 : 0 }; \
      pa = *(s16x8*)&_ti;                                                   \
    } while (0)
    s16x8 pa0, pa1, pa2;
    MKFRAG(pa0, c0a, c0b);
    MKFRAG(pa1, c1a, c1b);
    MKFRAG(pa2, c2a, c2b);
#undef MKFRAG

    f32x4 oa[4] = {};
#pragma unroll
    for (int dt = 0; dt < 4; ++dt) {
      oa[dt] = MFMA32(pa0, vfr[s0][dt], oa[dt]);
      if (i16 >= 1) oa[dt] = MFMA32(pa1, vfr[s1][dt], oa[dt]);
      if (i16 >= 2) oa[dt] = MFMA32(pa2, vfr[s2][dt], oa[dt]);
    }

#pragma unroll
    for (int dt = 0; dt < 4; ++dt) {
#pragma unroll
      for (int r = 0; r < 4; ++r) {
        int row = i16 * 16 + g * 4 + r;
        unsigned addr = (unsigned)(row * 512 + head * 128 + dt * 32 + c15 * 2);
        addr ^= ((unsigned)(row & 7)) << 4;
        *(u16*)((char*)Osh + addr) = (u16)f2bf(oa[dt][r]);
      }
    }
  }
#undef LOADKV

  __syncthreads();

  s16x8 afr[2][8];
#pragma unroll
  for (int mt = 0; mt < 2; ++mt) {
#pragma unroll
    for (int ks = 0; ks < 8; ++ks) {
      int row = wid * 32 + mt * 16 + c15;
      unsigned addr = ((unsigned)(row * 512 + ks * 64 + g * 16)) ^ (((unsigned)(row & 7)) << 4);
      afr[mt][ks] = *(const s16x8*)((const char*)Osh + addr);
    }
  }
  const int wbase = win * 256;
  for (int nt = 0; nt < 16; ++nt) {
    s16x8 bfr[8];
#pragma unroll
    for (int ks = 0; ks < 8; ++ks)
      bfr[ks] = *(const s16x8*)(wprojT + (nt * 16 + c15) * 256 + ks * 32 + g * 8);
    const float bv = bias[nt * 16 + c15];
    f32x4 a0 = {bv, bv, bv, bv};
    f32x4 a1 = {bv, bv, bv, bv};
#pragma unroll
    for (int ks = 0; ks < 8; ++ks) {
      a0 = MFMA32(afr[0][ks], bfr[ks], a0);
      a1 = MFMA32(afr[1][ks], bfr[ks], a1);
    }
    const int m0 = wbase + wid * 32;
#pragma unroll
    for (int r = 0; r < 4; ++r) {
      out[(size_t)(m0 + g * 4 + r) * 256 + nt * 16 + c15] = a0[r];
      out[(size_t)(m0 + 16 + g * 4 + r) * 256 + nt * 16 + c15] = a1[r];
    }
  }
}

extern "C" void kernel_launch(void* const* d_in, const int* in_sizes, int n_in,
                              void* d_out, int out_size, void* d_ws, size_t ws_size,
                              hipStream_t stream) {
  (void)in_sizes; (void)n_in; (void)out_size;
  const float* x     = (const float*)d_in[0];
  const float* wqkv  = (const float*)d_in[1];
  const float* wproj = (const float*)d_in[2];
  const float* bias  = (const float*)d_in[3];
  float* out = (float*)d_out;
  char* ws = (char*)d_ws;

  const size_t wBytes = (size_t)768 * 256 * 2 + (size_t)256 * 256 * 2;  // 524288
  u16* wqkvT  = (u16*)ws;
  u16* wprojT = (u16*)(ws + (size_t)768 * 256 * 2);
  u16* qkvbuf = (u16*)(ws + wBytes);

  const size_t perWin = 393216;        // 3 * 256 * 256 * 2 B
  size_t avail = (ws_size > wBytes) ? (ws_size - wBytes) : 0;
  int cwMax = (int)(avail / perWin);
  if (cwMax < 1) return;
  if (cwMax > 256) cwMax = 256;
  if (cwMax >= 4) cwMax &= ~3;         // keep nmTiles % 8 == 0 for the XCD mapping

  k_prep<<<1024, 256, 0, stream>>>(wqkv, wproj, wqkvT, wprojT);

  for (int w0 = 0; w0 < 256; w0 += cwMax) {
    int cw = 256 - w0 < cwMax ? 256 - w0 : cwMax;
    int whichStride = cw * 65536;
    int nm = cw * 2;                   // 128-row M-tiles
    k_qkv<<<nm, 512, 0, stream>>>(x + (size_t)w0 * 65536, wqkvT, qkvbuf, whichStride, nm);
    k_attn_proj<<<cw, 512, 0, stream>>>(qkvbuf,
                                        qkvbuf + (size_t)whichStride,
                                        qkvbuf + (size_t)2 * whichStride,
                                        wprojT, bias,
                                        out + (size_t)w0 * 65536);
  }
}

// Round 9
// 145.341 us; speedup vs baseline: 1.8443x; 1.8443x over previous
//
#include <hip/hip_runtime.h>
#include <hip/hip_bf16.h>

typedef unsigned short u16;
typedef __attribute__((ext_vector_type(4))) float  f32x4;
typedef __attribute__((ext_vector_type(8))) short  s16x8;
typedef __attribute__((ext_vector_type(4))) short  s16x4;
typedef __attribute__((ext_vector_type(4))) int    i32x4;
typedef __attribute__((ext_vector_type(2))) unsigned int u32x2;

#define MFMA32(a,b,c) __builtin_amdgcn_mfma_f32_16x16x32_bf16((a),(b),(c),0,0,0)

__device__ __forceinline__ short f2bf(float f) {
  unsigned u = __float_as_uint(f);
  u = (u + 0x7fffu + ((u >> 16) & 1u)) >> 16;
  return (short)u;
}
__device__ __forceinline__ unsigned packbf(float lo, float hi) {
  return (unsigned)(u16)f2bf(lo) | ((unsigned)(u16)f2bf(hi) << 16);
}
// packed RNE f32x2 -> bf16x2 (v_cvt_pk_bf16_f32)
__device__ __forceinline__ unsigned cvtpk(float a, float b) {
  float2 f; f.x = a; f.y = b;
  __hip_bfloat162 h = __float22bfloat162_rn(f);
  unsigned u; __builtin_memcpy(&u, &h, 4); return u;
}

// Geometry: B=16,T=4096,C=256 -> 256 windows of W=256, H=4, DH=64, RADIUS=32 (33 keys/row)

// ---------------- K0: weight cast + transpose ----------------
__global__ __launch_bounds__(256) void k_prep(const float* __restrict__ wqkv,
                                              const float* __restrict__ wproj,
                                              u16* __restrict__ wqkvT,
                                              u16* __restrict__ wprojT) {
  int idx = blockIdx.x * 256 + threadIdx.x;
  if (idx < 768 * 256) {
    int n = idx >> 8, kk = idx & 255;
    wqkvT[idx] = (u16)f2bf(wqkv[kk * 768 + n]);
  } else {
    int j = idx - 768 * 256;            // 0 .. 65535
    int n = j >> 8, kk = j & 255;
    wprojT[j] = (u16)f2bf(wproj[kk * 256 + n]);
  }
}

// ---------------- K1: qkv = x @ Wqkv  (rows = nm*128, N=768, K=256), bf16 out ----------------
// v4: per-wave B-slice in REGISTERS (loaded once), A-tile in LDS (one barrier),
// barrier-free MFMA loop, NONTEMPORAL stores (no L2 write-allocate -> B stays L2-hot).
__global__ __launch_bounds__(512, 4) void k_qkv(const float* __restrict__ x,
                                                const u16* __restrict__ wqkvT,
                                                u16* __restrict__ qkvws,
                                                int whichStride, int nmTiles) {
  __shared__ u16 Ash[128 * 256];        // 64 KB, XOR-swizzled rows
  const int tid = threadIdx.x;
  const int lane = tid & 63, wid = tid >> 6;
  const int wm = wid & 1, wn = wid >> 1;   // 2M x 4N waves; wave tile 64M x 32N
  const int c15 = lane & 15, g = lane >> 4;

  // grid: nm*6 blocks, n-fastest within per-XCD contiguous m-chunk (bijective iff nm%8==0)
  int s = blockIdx.x, m, nIdx;
  if ((nmTiles & 7) == 0) {
    int xcd = s & 7, t = s >> 3;
    int lm = t / 6; nIdx = t - lm * 6; m = xcd * (nmTiles >> 3) + lm;
  } else { m = s / 6; nIdx = s - (s / 6) * 6; }
  const size_t Mbase = (size_t)m * 128;
  const int Nbase = nIdx * 128;

  // ---- B preload: this wave's 32-N x 256-K slice into registers (16 x 16B, coalesced) ----
  s16x8 breg[2][8];
#pragma unroll
  for (int nt = 0; nt < 2; ++nt) {
    int n = Nbase + wn * 32 + nt * 16 + c15;
#pragma unroll
    for (int kc = 0; kc < 8; ++kc)
      breg[nt][kc] = *(const s16x8*)(wqkvT + n * 256 + kc * 32 + g * 8);
  }

  // ---- stage x tile -> LDS bf16 (coalesced; 16 loads + 16 b64 writes/thread) ----
  {
    const int row = tid >> 2, q = tid & 3;
    const float* xp = x + (Mbase + row) * 256 + q * 4;
    const unsigned swz = ((unsigned)(row & 7)) << 4;
#pragma unroll
    for (int p = 0; p < 16; ++p) {
      f32x4 v = *(const f32x4*)(xp + p * 16);
      u32x2 pk = { cvtpk(v[0], v[1]), cvtpk(v[2], v[3]) };
      unsigned b = ((unsigned)(row * 512 + p * 32 + q * 8)) ^ swz;
      *(u32x2*)((char*)Ash + b) = pk;
    }
  }
  __syncthreads();   // the ONLY barrier

  // ---- barrier-free K loop: 8 kc x (4 ds_read_b128 + 8 MFMA) ----
  f32x4 acc[4][2] = {};
#pragma unroll
  for (int kc = 0; kc < 8; ++kc) {
    s16x8 af[4];
#pragma unroll
    for (int mt = 0; mt < 4; ++mt) {
      int row = wm * 64 + mt * 16 + c15;
      unsigned b = ((unsigned)(row * 512 + kc * 64 + g * 16)) ^ (((unsigned)(row & 7)) << 4);
      af[mt] = *(const s16x8*)((const char*)Ash + b);
    }
#pragma unroll
    for (int mt = 0; mt < 4; ++mt)
#pragma unroll
      for (int nt = 0; nt < 2; ++nt)
        acc[mt][nt] = MFMA32(af[mt], breg[nt][kc], acc[mt][nt]);
  }

  // ---- nontemporal scattered stores: n -> (which,h,d) ----
#pragma unroll
  for (int nt = 0; nt < 2; ++nt) {
    int n = Nbase + wn * 32 + nt * 16 + c15;
    int which = n >> 8, h = (n >> 6) & 3, dd = n & 63;
    size_t o0 = (size_t)which * whichStride + (size_t)h * 16384 + dd;
#pragma unroll
    for (int mt = 0; mt < 4; ++mt)
#pragma unroll
      for (int r = 0; r < 4; ++r) {
        size_t mg = Mbase + wm * 64 + mt * 16 + g * 4 + r;
        __builtin_nontemporal_store((u16)f2bf(acc[mt][nt][r]),
                                    qkvws + o0 + (mg >> 8) * 65536 + (mg & 255) * 64);
      }
  }
}

// ---------------- K2: per-window banded attention + output projection ----------------
__global__ __launch_bounds__(512) void k_attn_proj(const u16* __restrict__ qws,
                                                   const u16* __restrict__ kws,
                                                   const u16* __restrict__ vws,
                                                   const u16* __restrict__ wprojT,
                                                   const float* __restrict__ bias,
                                                   float* __restrict__ out) {
  __shared__ u16 Osh[256 * 256];  // attn output [row][C] bf16, XOR-swizzled, 128 KiB
  const int tid = threadIdx.x;
  const int lane = tid & 63, wid = tid >> 6;
  const int head = wid >> 1, qhalf = wid & 1;
  const int c15 = lane & 15, g = lane >> 4;
  const int win = blockIdx.x;

  const size_t hb = (size_t)(win * 4 + head) * 16384;  // 256*64 per (win,head)
  const u16* Qp = qws + hb;
  const u16* Kp = kws + hb;
  const u16* Vp = vws + hb;
  const int start = qhalf * 8;          // this wave's Q-tiles: [start, start+8); start % 4 == 0

  // 4-slot register rings (slot = jt & 3): K fragments (A-layout) and V fragments (B-layout)
  s16x8 klo[4] = {}, khi[4] = {};
  s16x8 vfr[4][4] = {};

#define LOADKV(jt, slot) do {                                                \
    const u16* _p = Kp + (jt) * 1024 + c15 * 64 + g * 8;                     \
    klo[slot] = *(const s16x8*)_p;                                           \
    khi[slot] = *(const s16x8*)(_p + 32);                                    \
    const int _rb = (jt) * 16 + ((g & 1) << 3);                              \
    _Pragma("unroll")                                                        \
    for (int _dt = 0; _dt < 4; ++_dt) {                                      \
      s16x8 _t;                                                              \
      _Pragma("unroll")                                                      \
      for (int _i = 0; _i < 8; ++_i)                                         \
        _t[_i] = (short)Vp[(_rb + _i) * 64 + _dt * 16 + c15];                \
      vfr[slot][_dt] = _t;                                                   \
    }                                                                        \
  } while (0)

  if (start >= 2) LOADKV(start - 2, 2);
  if (start >= 1) LOADKV(start - 1, 3);
  LOADKV(start, 0);

#pragma unroll
  for (int ii = 0; ii < 8; ++ii) {
    const int i16 = start + ii;
    const int sP = (ii + 1) & 3;
    const int s0 = ii & 3;
    const int s1 = (ii + 3) & 3;
    const int s2 = (ii + 2) & 3;
    if (ii < 7) LOADKV(i16 + 1, sP);   // prefetch next K/V tile

    const u16* qp = Qp + i16 * 1024 + c15 * 64 + g * 8;
    const s16x8 qf0 = *(const s16x8*)qp;
    const s16x8 qf1 = *(const s16x8*)(qp + 32);

    // S^T[j][q] = sum_d K[j][d] Q[q][d]; lane holds j = jt*16 + g*4 + r, q = c15
    f32x4 sT0 = {}, sT1 = {}, sT2 = {};
    sT0 = MFMA32(klo[s0], qf0, sT0);
    sT0 = MFMA32(khi[s0], qf1, sT0);
    if (i16 >= 1) { sT1 = MFMA32(klo[s1], qf0, sT1); sT1 = MFMA32(khi[s1], qf1, sT1); }
    if (i16 >= 2) { sT2 = MFMA32(klo[s2], qf0, sT2); sT2 = MFMA32(khi[s2], qf1, sT2); }

    const int qrow = i16 * 16 + c15;
    float e0[4], e1[4], e2[4];
    float vmax = -3.0e38f;
#pragma unroll
    for (int r = 0; r < 4; ++r) {
      int dd = qrow - (i16 * 16 + g * 4 + r);
      e0[r] = (dd >= 0 && dd <= 32) ? sT0[r] * 0.125f : -1.0e30f;
      vmax = fmaxf(vmax, e0[r]);
    }
    if (i16 >= 1) {
#pragma unroll
      for (int r = 0; r < 4; ++r) {           // dd in 1..31, always in band
        e1[r] = sT1[r] * 0.125f;
        vmax = fmaxf(vmax, e1[r]);
      }
    }
    if (i16 >= 2) {
#pragma unroll
      for (int r = 0; r < 4; ++r) {
        int dd = qrow - ((i16 - 2) * 16 + g * 4 + r);   // 17..47
        e2[r] = (dd <= 32) ? sT2[r] * 0.125f : -1.0e30f;
        vmax = fmaxf(vmax, e2[r]);
      }
    }
    vmax = fmaxf(vmax, __shfl_xor(vmax, 16));
    vmax = fmaxf(vmax, __shfl_xor(vmax, 32));
    float ssum = 0.0f;
#pragma unroll
    for (int r = 0; r < 4; ++r) { e0[r] = __expf(e0[r] - vmax); ssum += e0[r]; }
    if (i16 >= 1) {
#pragma unroll
      for (int r = 0; r < 4; ++r) { e1[r] = __expf(e1[r] - vmax); ssum += e1[r]; }
    }
    if (i16 >= 2) {
#pragma unroll
      for (int r = 0; r < 4; ++r) { e2[r] = __expf(e2[r] - vmax); ssum += e2[r]; }
    }
    ssum += __shfl_xor(ssum, 16);
    ssum += __shfl_xor(ssum, 32);
    const float inv = 1.0f / ssum;

    unsigned c0a = packbf(e0[0] * inv, e0[1] * inv), c0b = packbf(e0[2] * inv, e0[3] * inv);
    unsigned c1a = 0, c1b = 0, c2a = 0, c2b = 0;
    if (i16 >= 1) { c1a = packbf(e1[0] * inv, e1[1] * inv); c1b = packbf(e1[2] * inv, e1[3] * inv); }
    if (i16 >= 2) { c2a = packbf(e2[0] * inv, e2[1] * inv); c2b = packbf(e2[2] * inv, e2[3] * inv); }

    const int src0 = ((g & 1) << 5) + c15;
    const int src1 = src0 + 16;
    const bool alo = (g < 2);
#define MKFRAG(pa, ua, ub) do {                                             \
      int _t0 = __shfl((int)(ua), src0), _t1 = __shfl((int)(ub), src0);     \
      int _t2 = __shfl((int)(ua), src1), _t3 = __shfl((int)(ub), src1);     \
      i32x4 _ti = { alo ? _t0 : 0, alo ? _t1 : 0, alo ? _t2 : 0, alo ? _t3 : 0 }; \
      pa = *(s16x8*)&_ti;                                                   \
    } while (0)
    s16x8 pa0, pa1, pa2;
    MKFRAG(pa0, c0a, c0b);
    MKFRAG(pa1, c1a, c1b);
    MKFRAG(pa2, c2a, c2b);
#undef MKFRAG

    f32x4 oa[4] = {};
#pragma unroll
    for (int dt = 0; dt < 4; ++dt) {
      oa[dt] = MFMA32(pa0, vfr[s0][dt], oa[dt]);
      if (i16 >= 1) oa[dt] = MFMA32(pa1, vfr[s1][dt], oa[dt]);
      if (i16 >= 2) oa[dt] = MFMA32(pa2, vfr[s2][dt], oa[dt]);
    }

#pragma unroll
    for (int dt = 0; dt < 4; ++dt) {
#pragma unroll
      for (int r = 0; r < 4; ++r) {
        int row = i16 * 16 + g * 4 + r;
        unsigned addr = (unsigned)(row * 512 + head * 128 + dt * 32 + c15 * 2);
        addr ^= ((unsigned)(row & 7)) << 4;
        *(u16*)((char*)Osh + addr) = (u16)f2bf(oa[dt][r]);
      }
    }
  }
#undef LOADKV

  __syncthreads();

  s16x8 afr[2][8];
#pragma unroll
  for (int mt = 0; mt < 2; ++mt) {
#pragma unroll
    for (int ks = 0; ks < 8; ++ks) {
      int row = wid * 32 + mt * 16 + c15;
      unsigned addr = ((unsigned)(row * 512 + ks * 64 + g * 16)) ^ (((unsigned)(row & 7)) << 4);
      afr[mt][ks] = *(const s16x8*)((const char*)Osh + addr);
    }
  }
  const int wbase = win * 256;
  for (int nt = 0; nt < 16; ++nt) {
    s16x8 bfr[8];
#pragma unroll
    for (int ks = 0; ks < 8; ++ks)
      bfr[ks] = *(const s16x8*)(wprojT + (nt * 16 + c15) * 256 + ks * 32 + g * 8);
    const float bv = bias[nt * 16 + c15];
    f32x4 a0 = {bv, bv, bv, bv};
    f32x4 a1 = {bv, bv, bv, bv};
#pragma unroll
    for (int ks = 0; ks < 8; ++ks) {
      a0 = MFMA32(afr[0][ks], bfr[ks], a0);
      a1 = MFMA32(afr[1][ks], bfr[ks], a1);
    }
    const int m0 = wbase + wid * 32;
#pragma unroll
    for (int r = 0; r < 4; ++r) {
      out[(size_t)(m0 + g * 4 + r) * 256 + nt * 16 + c15] = a0[r];
      out[(size_t)(m0 + 16 + g * 4 + r) * 256 + nt * 16 + c15] = a1[r];
    }
  }
}

extern "C" void kernel_launch(void* const* d_in, const int* in_sizes, int n_in,
                              void* d_out, int out_size, void* d_ws, size_t ws_size,
                              hipStream_t stream) {
  (void)in_sizes; (void)n_in; (void)out_size;
  const float* x     = (const float*)d_in[0];
  const float* wqkv  = (const float*)d_in[1];
  const float* wproj = (const float*)d_in[2];
  const float* bias  = (const float*)d_in[3];
  float* out = (float*)d_out;
  char* ws = (char*)d_ws;

  const size_t wBytes = (size_t)768 * 256 * 2 + (size_t)256 * 256 * 2;  // 524288
  u16* wqkvT  = (u16*)ws;
  u16* wprojT = (u16*)(ws + (size_t)768 * 256 * 2);
  u16* qkvbuf = (u16*)(ws + wBytes);

  const size_t perWin = 393216;        // 3 * 256 * 256 * 2 B
  size_t avail = (ws_size > wBytes) ? (ws_size - wBytes) : 0;
  int cwMax = (int)(avail / perWin);
  if (cwMax < 1) return;
  if (cwMax > 256) cwMax = 256;
  if (cwMax >= 4) cwMax &= ~3;         // keep nmTiles % 8 == 0 for the XCD mapping

  k_prep<<<1024, 256, 0, stream>>>(wqkv, wproj, wqkvT, wprojT);

  for (int w0 = 0; w0 < 256; w0 += cwMax) {
    int cw = 256 - w0 < cwMax ? 256 - w0 : cwMax;
    int whichStride = cw * 65536;
    int nm = cw * 2;                   // 128-row M-tiles
    k_qkv<<<nm * 6, 512, 0, stream>>>(x + (size_t)w0 * 65536, wqkvT, qkvbuf, whichStride, nm);
    k_attn_proj<<<cw, 512, 0, stream>>>(qkvbuf,
                                        qkvbuf + (size_t)whichStride,
                                        qkvbuf + (size_t)2 * whichStride,
                                        wprojT, bias,
                                        out + (size_t)w0 * 65536);
  }
}

// Round 10
// 124.305 us; speedup vs baseline: 2.1564x; 1.1692x over previous
//
#include <hip/hip_runtime.h>
#include <hip/hip_bf16.h>

typedef unsigned short u16;
typedef __attribute__((ext_vector_type(4))) float  f32x4;
typedef __attribute__((ext_vector_type(8))) short  s16x8;
typedef __attribute__((ext_vector_type(4))) short  s16x4;
typedef __attribute__((ext_vector_type(4))) int    i32x4;
typedef __attribute__((ext_vector_type(2))) unsigned int u32x2;

#define MFMA32(a,b,c) __builtin_amdgcn_mfma_f32_16x16x32_bf16((a),(b),(c),0,0,0)

__device__ __forceinline__ short f2bf(float f) {
  unsigned u = __float_as_uint(f);
  u = (u + 0x7fffu + ((u >> 16) & 1u)) >> 16;
  return (short)u;
}
__device__ __forceinline__ unsigned packbf(float lo, float hi) {
  return (unsigned)(u16)f2bf(lo) | ((unsigned)(u16)f2bf(hi) << 16);
}
// packed RNE f32x2 -> bf16x2 (v_cvt_pk_bf16_f32)
__device__ __forceinline__ unsigned cvtpk(float a, float b) {
  float2 f; f.x = a; f.y = b;
  __hip_bfloat162 h = __float22bfloat162_rn(f);
  unsigned u; __builtin_memcpy(&u, &h, 4); return u;
}

// Geometry: B=16,T=4096,C=256 -> 256 windows of W=256, H=4, DH=64, RADIUS=32 (33 keys/row)

// ---------------- K0: weight cast + transpose ----------------
__global__ __launch_bounds__(256) void k_prep(const float* __restrict__ wqkv,
                                              const float* __restrict__ wproj,
                                              u16* __restrict__ wqkvT,
                                              u16* __restrict__ wprojT) {
  int idx = blockIdx.x * 256 + threadIdx.x;
  if (idx < 768 * 256) {
    int n = idx >> 8, kk = idx & 255;
    wqkvT[idx] = (u16)f2bf(wqkv[kk * 768 + n]);
  } else {
    int j = idx - 768 * 256;            // 0 .. 65535
    int n = j >> 8, kk = j & 255;
    wprojT[j] = (u16)f2bf(wproj[kk * 256 + n]);
  }
}

// ---------------- K1: qkv = x @ Wqkv  (rows = nm*128, N=768, K=256), bf16 out ----------------
// v5: B-slice in REGISTERS (loaded once, immune to L2 eviction), A-tile in LDS (one
// barrier), barrier-free K loop, then LDS-transposed COALESCED epilogue through L2.
__global__ __launch_bounds__(512, 4) void k_qkv(const float* __restrict__ x,
                                                const u16* __restrict__ wqkvT,
                                                u16* __restrict__ qkvws,
                                                int whichStride, int nmTiles) {
  __shared__ u16 Ash[128 * 256];        // 64 KB, XOR-swizzled rows; reused as C-tile
  const int tid = threadIdx.x;
  const int lane = tid & 63, wid = tid >> 6;
  const int wm = wid & 1, wn = wid >> 1;   // 2M x 4N waves; wave tile 64M x 32N
  const int c15 = lane & 15, g = lane >> 4;

  // grid: nm*6 blocks, n-fastest within per-XCD contiguous m-chunk (bijective iff nm%8==0)
  int s = blockIdx.x, m, nIdx;
  if ((nmTiles & 7) == 0) {
    int xcd = s & 7, t = s >> 3;
    int lm = t / 6; nIdx = t - lm * 6; m = xcd * (nmTiles >> 3) + lm;
  } else { m = s / 6; nIdx = s - (s / 6) * 6; }
  const size_t Mbase = (size_t)m * 128;
  const int Nbase = nIdx * 128;

  // ---- B preload: this wave's 32-N x 256-K slice into registers (16 x 16B, coalesced) ----
  s16x8 breg[2][8];
#pragma unroll
  for (int nt = 0; nt < 2; ++nt) {
    int n = Nbase + wn * 32 + nt * 16 + c15;
#pragma unroll
    for (int kc = 0; kc < 8; ++kc)
      breg[nt][kc] = *(const s16x8*)(wqkvT + n * 256 + kc * 32 + g * 8);
  }

  // ---- stage x tile -> LDS bf16 (coalesced; 16 loads + 16 b64 writes/thread) ----
  {
    const int row = tid >> 2, q = tid & 3;
    const float* xp = x + (Mbase + row) * 256 + q * 4;
    const unsigned swz = ((unsigned)(row & 7)) << 4;
#pragma unroll
    for (int p = 0; p < 16; ++p) {
      f32x4 v = *(const f32x4*)(xp + p * 16);
      u32x2 pk = { cvtpk(v[0], v[1]), cvtpk(v[2], v[3]) };
      unsigned b = ((unsigned)(row * 512 + p * 32 + q * 8)) ^ swz;
      *(u32x2*)((char*)Ash + b) = pk;
    }
  }
  __syncthreads();

  // ---- barrier-free K loop: 8 kc x (4 ds_read_b128 + 8 MFMA) ----
  f32x4 acc[4][2] = {};
#pragma unroll
  for (int kc = 0; kc < 8; ++kc) {
    s16x8 af[4];
#pragma unroll
    for (int mt = 0; mt < 4; ++mt) {
      int row = wm * 64 + mt * 16 + c15;
      unsigned b = ((unsigned)(row * 512 + kc * 64 + g * 16)) ^ (((unsigned)(row & 7)) << 4);
      af[mt] = *(const s16x8*)((const char*)Ash + b);
    }
#pragma unroll
    for (int mt = 0; mt < 4; ++mt)
#pragma unroll
      for (int nt = 0; nt < 2; ++nt)
        acc[mt][nt] = MFMA32(af[mt], breg[nt][kc], acc[mt][nt]);
  }

  // ---- epilogue: acc -> LDS [128][128] u16 (swizzled) -> 16B/lane coalesced stores ----
  __syncthreads();                       // all Ash reads done
  u16* Csh = Ash;                        // 32 KB of the 64 KB
#pragma unroll
  for (int mt = 0; mt < 4; ++mt)
#pragma unroll
    for (int nt = 0; nt < 2; ++nt)
#pragma unroll
      for (int r = 0; r < 4; ++r) {
        int mm = wm * 64 + mt * 16 + g * 4 + r;
        int nn = wn * 32 + nt * 16 + c15;
        unsigned addr = (unsigned)(mm * 256 + nn * 2) ^ (((unsigned)(mm & 7)) << 4);
        *(u16*)((char*)Csh + addr) = (u16)f2bf(acc[mt][nt][r]);
      }
  __syncthreads();

#pragma unroll
  for (int i = 0; i < 4; ++i) {
    int c = tid + 512 * i;               // 0..2047 (16B chunks of the 128x128 tile)
    int mm = c >> 4;                     // 0..127
    int n0 = (c & 15) * 8;               // stays inside one 64-d head group
    unsigned addr = (unsigned)(mm * 256 + n0 * 2) ^ (((unsigned)(mm & 7)) << 4);
    i32x4 v = *(const i32x4*)((const char*)Csh + addr);
    int n = Nbase + n0;
    int which = n >> 8, h = (n >> 6) & 3, dd = n & 63;
    size_t mg = Mbase + mm;
    size_t o = (size_t)which * whichStride + (size_t)h * 16384
             + (mg >> 8) * 65536 + (mg & 255) * 64 + dd;
    *(i32x4*)(qkvws + o) = v;
  }
}

// ---------------- K2: per-window banded attention + output projection ----------------
__global__ __launch_bounds__(512) void k_attn_proj(const u16* __restrict__ qws,
                                                   const u16* __restrict__ kws,
                                                   const u16* __restrict__ vws,
                                                   const u16* __restrict__ wprojT,
                                                   const float* __restrict__ bias,
                                                   float* __restrict__ out) {
  __shared__ u16 Osh[256 * 256];  // attn output [row][C] bf16, XOR-swizzled, 128 KiB
  const int tid = threadIdx.x;
  const int lane = tid & 63, wid = tid >> 6;
  const int head = wid >> 1, qhalf = wid & 1;
  const int c15 = lane & 15, g = lane >> 4;
  const int win = blockIdx.x;

  const size_t hb = (size_t)(win * 4 + head) * 16384;  // 256*64 per (win,head)
  const u16* Qp = qws + hb;
  const u16* Kp = kws + hb;
  const u16* Vp = vws + hb;
  const int start = qhalf * 8;          // this wave's Q-tiles: [start, start+8); start % 4 == 0

  // 4-slot register rings (slot = jt & 3): K fragments (A-layout) and V fragments (B-layout)
  s16x8 klo[4] = {}, khi[4] = {};
  s16x8 vfr[4][4] = {};

#define LOADKV(jt, slot) do {                                                \
    const u16* _p = Kp + (jt) * 1024 + c15 * 64 + g * 8;                     \
    klo[slot] = *(const s16x8*)_p;                                           \
    khi[slot] = *(const s16x8*)(_p + 32);                                    \
    const int _rb = (jt) * 16 + ((g & 1) << 3);                              \
    _Pragma("unroll")                                                        \
    for (int _dt = 0; _dt < 4; ++_dt) {                                      \
      s16x8 _t;                                                              \
      _Pragma("unroll")                                                      \
      for (int _i = 0; _i < 8; ++_i)                                         \
        _t[_i] = (short)Vp[(_rb + _i) * 64 + _dt * 16 + c15];                \
      vfr[slot][_dt] = _t;                                                   \
    }                                                                        \
  } while (0)

  if (start >= 2) LOADKV(start - 2, 2);
  if (start >= 1) LOADKV(start - 1, 3);
  LOADKV(start, 0);

#pragma unroll
  for (int ii = 0; ii < 8; ++ii) {
    const int i16 = start + ii;
    const int sP = (ii + 1) & 3;
    const int s0 = ii & 3;
    const int s1 = (ii + 3) & 3;
    const int s2 = (ii + 2) & 3;
    if (ii < 7) LOADKV(i16 + 1, sP);   // prefetch next K/V tile

    const u16* qp = Qp + i16 * 1024 + c15 * 64 + g * 8;
    const s16x8 qf0 = *(const s16x8*)qp;
    const s16x8 qf1 = *(const s16x8*)(qp + 32);

    // S^T[j][q] = sum_d K[j][d] Q[q][d]; lane holds j = jt*16 + g*4 + r, q = c15
    f32x4 sT0 = {}, sT1 = {}, sT2 = {};
    sT0 = MFMA32(klo[s0], qf0, sT0);
    sT0 = MFMA32(khi[s0], qf1, sT0);
    if (i16 >= 1) { sT1 = MFMA32(klo[s1], qf0, sT1); sT1 = MFMA32(khi[s1], qf1, sT1); }
    if (i16 >= 2) { sT2 = MFMA32(klo[s2], qf0, sT2); sT2 = MFMA32(khi[s2], qf1, sT2); }

    const int qrow = i16 * 16 + c15;
    float e0[4], e1[4], e2[4];
    float vmax = -3.0e38f;
#pragma unroll
    for (int r = 0; r < 4; ++r) {
      int dd = qrow - (i16 * 16 + g * 4 + r);
      e0[r] = (dd >= 0 && dd <= 32) ? sT0[r] * 0.125f : -1.0e30f;
      vmax = fmaxf(vmax, e0[r]);
    }
    if (i16 >= 1) {
#pragma unroll
      for (int r = 0; r < 4; ++r) {           // dd in 1..31, always in band
        e1[r] = sT1[r] * 0.125f;
        vmax = fmaxf(vmax, e1[r]);
      }
    }
    if (i16 >= 2) {
#pragma unroll
      for (int r = 0; r < 4; ++r) {
        int dd = qrow - ((i16 - 2) * 16 + g * 4 + r);   // 17..47
        e2[r] = (dd <= 32) ? sT2[r] * 0.125f : -1.0e30f;
        vmax = fmaxf(vmax, e2[r]);
      }
    }
    vmax = fmaxf(vmax, __shfl_xor(vmax, 16));
    vmax = fmaxf(vmax, __shfl_xor(vmax, 32));
    float ssum = 0.0f;
#pragma unroll
    for (int r = 0; r < 4; ++r) { e0[r] = __expf(e0[r] - vmax); ssum += e0[r]; }
    if (i16 >= 1) {
#pragma unroll
      for (int r = 0; r < 4; ++r) { e1[r] = __expf(e1[r] - vmax); ssum += e1[r]; }
    }
    if (i16 >= 2) {
#pragma unroll
      for (int r = 0; r < 4; ++r) { e2[r] = __expf(e2[r] - vmax); ssum += e2[r]; }
    }
    ssum += __shfl_xor(ssum, 16);
    ssum += __shfl_xor(ssum, 32);
    const float inv = 1.0f / ssum;

    unsigned c0a = packbf(e0[0] * inv, e0[1] * inv), c0b = packbf(e0[2] * inv, e0[3] * inv);
    unsigned c1a = 0, c1b = 0, c2a = 0, c2b = 0;
    if (i16 >= 1) { c1a = packbf(e1[0] * inv, e1[1] * inv); c1b = packbf(e1[2] * inv, e1[3] * inv); }
    if (i16 >= 2) { c2a = packbf(e2[0] * inv, e2[1] * inv); c2b = packbf(e2[2] * inv, e2[3] * inv); }

    const int src0 = ((g & 1) << 5) + c15;
    const int src1 = src0 + 16;
    const bool alo = (g < 2);
#define MKFRAG(pa, ua, ub) do {                                             \
      int _t0 = __shfl((int)(ua), src0), _t1 = __shfl((int)(ub), src0);     \
      int _t2 = __shfl((int)(ua), src1), _t3 = __shfl((int)(ub), src1);     \
      i32x4 _ti = { alo ? _t0 : 0, alo ? _t1 : 0, alo ? _t2 : 0, alo ? _t3 : 0 }; \
      pa = *(s16x8*)&_ti;                                                   \
    } while (0)
    s16x8 pa0, pa1, pa2;
    MKFRAG(pa0, c0a, c0b);
    MKFRAG(pa1, c1a, c1b);
    MKFRAG(pa2, c2a, c2b);
#undef MKFRAG

    f32x4 oa[4] = {};
#pragma unroll
    for (int dt = 0; dt < 4; ++dt) {
      oa[dt] = MFMA32(pa0, vfr[s0][dt], oa[dt]);
      if (i16 >= 1) oa[dt] = MFMA32(pa1, vfr[s1][dt], oa[dt]);
      if (i16 >= 2) oa[dt] = MFMA32(pa2, vfr[s2][dt], oa[dt]);
    }

#pragma unroll
    for (int dt = 0; dt < 4; ++dt) {
#pragma unroll
      for (int r = 0; r < 4; ++r) {
        int row = i16 * 16 + g * 4 + r;
        unsigned addr = (unsigned)(row * 512 + head * 128 + dt * 32 + c15 * 2);
        addr ^= ((unsigned)(row & 7)) << 4;
        *(u16*)((char*)Osh + addr) = (u16)f2bf(oa[dt][r]);
      }
    }
  }
#undef LOADKV

  __syncthreads();

  s16x8 afr[2][8];
#pragma unroll
  for (int mt = 0; mt < 2; ++mt) {
#pragma unroll
    for (int ks = 0; ks < 8; ++ks) {
      int row = wid * 32 + mt * 16 + c15;
      unsigned addr = ((unsigned)(row * 512 + ks * 64 + g * 16)) ^ (((unsigned)(row & 7)) << 4);
      afr[mt][ks] = *(const s16x8*)((const char*)Osh + addr);
    }
  }
  const int wbase = win * 256;
  for (int nt = 0; nt < 16; ++nt) {
    s16x8 bfr[8];
#pragma unroll
    for (int ks = 0; ks < 8; ++ks)
      bfr[ks] = *(const s16x8*)(wprojT + (nt * 16 + c15) * 256 + ks * 32 + g * 8);
    const float bv = bias[nt * 16 + c15];
    f32x4 a0 = {bv, bv, bv, bv};
    f32x4 a1 = {bv, bv, bv, bv};
#pragma unroll
    for (int ks = 0; ks < 8; ++ks) {
      a0 = MFMA32(afr[0][ks], bfr[ks], a0);
      a1 = MFMA32(afr[1][ks], bfr[ks], a1);
    }
    const int m0 = wbase + wid * 32;
#pragma unroll
    for (int r = 0; r < 4; ++r) {
      out[(size_t)(m0 + g * 4 + r) * 256 + nt * 16 + c15] = a0[r];
      out[(size_t)(m0 + 16 + g * 4 + r) * 256 + nt * 16 + c15] = a1[r];
    }
  }
}

extern "C" void kernel_launch(void* const* d_in, const int* in_sizes, int n_in,
                              void* d_out, int out_size, void* d_ws, size_t ws_size,
                              hipStream_t stream) {
  (void)in_sizes; (void)n_in; (void)out_size;
  const float* x     = (const float*)d_in[0];
  const float* wqkv  = (const float*)d_in[1];
  const float* wproj = (const float*)d_in[2];
  const float* bias  = (const float*)d_in[3];
  float* out = (float*)d_out;
  char* ws = (char*)d_ws;

  const size_t wBytes = (size_t)768 * 256 * 2 + (size_t)256 * 256 * 2;  // 524288
  u16* wqkvT  = (u16*)ws;
  u16* wprojT = (u16*)(ws + (size_t)768 * 256 * 2);
  u16* qkvbuf = (u16*)(ws + wBytes);

  const size_t perWin = 393216;        // 3 * 256 * 256 * 2 B
  size_t avail = (ws_size > wBytes) ? (ws_size - wBytes) : 0;
  int cwMax = (int)(avail / perWin);
  if (cwMax < 1) return;
  if (cwMax > 256) cwMax = 256;
  if (cwMax >= 4) cwMax &= ~3;         // keep nmTiles % 8 == 0 for the XCD mapping

  k_prep<<<1024, 256, 0, stream>>>(wqkv, wproj, wqkvT, wprojT);

  for (int w0 = 0; w0 < 256; w0 += cwMax) {
    int cw = 256 - w0 < cwMax ? 256 - w0 : cwMax;
    int whichStride = cw * 65536;
    int nm = cw * 2;                   // 128-row M-tiles
    k_qkv<<<nm * 6, 512, 0, stream>>>(x + (size_t)w0 * 65536, wqkvT, qkvbuf, whichStride, nm);
    k_attn_proj<<<cw, 512, 0, stream>>>(qkvbuf,
                                        qkvbuf + (size_t)whichStride,
                                        qkvbuf + (size_t)2 * whichStride,
                                        wprojT, bias,
                                        out + (size_t)w0 * 65536);
  }
}